// Round 9
// baseline (207.852 us; speedup 1.0000x reference)
//
#include <hip/hip_runtime.h>
#include <limits.h>

typedef __attribute__((ext_vector_type(8))) short short8v;
typedef __attribute__((ext_vector_type(4))) float f32x4;

#define W_  128
#define HW_ 16384

#define MFMA32(a, b, c) __builtin_amdgcn_mfma_f32_16x16x32_bf16(a, b, c, 0, 0, 0)

__device__ __forceinline__ short bf16b(float f) {
    unsigned u = __float_as_uint(f);
    u += 0x7fffu + ((u >> 16) & 1u);   // RNE
    return (short)(u >> 16);
}
__device__ __forceinline__ unsigned bf16pk(float lo, float hi) {
    unsigned ul = __float_as_uint(lo);
    ul += 0x7fffu + ((ul >> 16) & 1u);
    unsigned uh = __float_as_uint(hi);
    uh += 0x7fffu + ((uh >> 16) & 1u);
    return (ul >> 16) | (uh & 0xffff0000u);
}

// 1024 threads = 16 waves; tile 16h x 16w, all 81 displacements.
// Wave wid owns ONE output row: acc[9][2] = 72 regs.
// __launch_bounds__(1024, 4): 4 waves/SIMD -> 128-VGPR budget. Round-8 lesson:
// omitting the 2nd arg let the compiler pick a 64-reg budget and spill acc
// (VGPR_Count=64, WRITE 101MB, 177us). Staged in2 kept as PACKED bf16 dwords
// (sp[3][4] = 12 regs across the barrier, not 24).
// Single 48KB in2 buffer [r24][j4][col32][8k bf16], per-(r,j) dword rotation
// ROT=((r*4+j)&7)*4 mod 128 on write and read (validated round 8, absmax 0.5).
// Junk cols 24..31: never written, feed only never-read acc elements.
// 2 barriers per chunk; in2 prefetch for t+1 issues BEFORE MFMA (latency under
// compute), packed after. Epilogue: one barrier pair, 84KB ldso aliases buffer.
// NOTE: all acc[][] indices compile-time constant (round-3 lesson: runtime
// index -> scratch demotion).
__global__ __launch_bounds__(1024, 4)
void corr_kernel(const float* __restrict__ in1, const float* __restrict__ in2,
                 float* __restrict__ out)
{
    __shared__ __attribute__((aligned(16))) unsigned char smem[84992];
    short*    lds  = (short*)smem;      // staging view (48KB used)
    unsigned* ldsI = (unsigned*)smem;   // dword view for packed writes
    float*    ldso = (float*)smem;      // epilogue view (81*260*4 = 84240B)

    const int tid  = threadIdx.x;
    const int lane = tid & 63;
    const int wid  = tid >> 6;        // 0..15 = output row within tile
    const int m    = lane & 15;       // M row / N col in 16x16 tile
    const int g    = lane >> 4;       // k-octet 0..3

    int bid = blockIdx.x;
    int swz = (bid & 7) * 64 + (bid >> 3);       // bijective XCD swizzle; 1 image/XCD
    int n   = swz >> 6;
    int h0  = ((swz >> 3) & 7) << 4;
    int w0  = (swz & 7) << 4;

    const float* in1n = in1 + (size_t)n * (256 * HW_);
    const float* in2n = in2 + (size_t)n * (256 * HW_);

    // ---- staging geometry: pair-unit u = (r*16+kp)*6+q, 2304 units ----
    int gof0[3], wbas[3], wrot[3];
    bool act[3];
#pragma unroll
    for (int s = 0; s < 3; ++s) {
        int u    = tid + s * 1024;
        act[s]   = (u < 2304);
        int q    = u % 6;
        int rest = u / 6;
        int kp   = rest & 15;
        int r    = rest >> 4;         // 0..23
        int row  = h0 - 4 + r;
        int col0 = w0 - 4 + 4 * q;
        bool inb = act[s] && ((unsigned)row < 128u) && ((unsigned)col0 < 125u);
        int  cc  = 8 * (kp >> 2) + 2 * (kp & 3);
        gof0[s]  = inb ? (cc * HW_ + row * W_ + col0) : INT_MIN;
        int rj   = r * 4 + (kp >> 2);
        wbas[s]  = rj * 128;
        wrot[s]  = 16 * q + (kp & 3) + ((rj & 7) << 2);
    }
    const int abase = (8 * g) * HW_ + (h0 + wid) * W_ + (w0 + m);

    f32x4 acc[9][2];
#pragma unroll
    for (int d = 0; d < 9; ++d)
#pragma unroll
        for (int t = 0; t < 2; ++t)
            acc[d][t] = (f32x4){0.f, 0.f, 0.f, 0.f};

    // ---- prologue: load + pack chunk 0 (in2) and load A chunk 0 ----
    unsigned sp[3][4];
    float af[8];
    {
        f32x4 sf0[3], sf1[3];
#pragma unroll
        for (int s = 0; s < 3; ++s) {
            f32x4 v0 = (f32x4){0.f, 0.f, 0.f, 0.f}, v1 = v0;
            if (gof0[s] != INT_MIN) {
                v0 = *(const f32x4*)(in2n + gof0[s]);
                v1 = *(const f32x4*)(in2n + gof0[s] + HW_);
            }
            sf0[s] = v0; sf1[s] = v1;
        }
#pragma unroll
        for (int s = 0; s < 3; ++s)
#pragma unroll
            for (int d = 0; d < 4; ++d)
                sp[s][d] = bf16pk(sf0[s][d], sf1[s][d]);
    }
#pragma unroll
    for (int i = 0; i < 8; ++i) af[i] = in1n[abase + i * HW_];

    // ---- main loop: 8 chunks of 32 channels; 2 barriers per chunk ----
#pragma unroll 1
    for (int t = 0; t < 8; ++t) {
        // stage chunk t (rotated pair-packed dword writes, from sp)
#pragma unroll
        for (int s = 0; s < 3; ++s)
            if (act[s]) {
#pragma unroll
                for (int d = 0; d < 4; ++d)
                    ldsI[wbas[s] + ((wrot[s] + 4 * d) & 127)] = sp[s][d];
            }
        __syncthreads();
        __builtin_amdgcn_sched_barrier(0);

        // A frags for chunk t
        short8v a8;
#pragma unroll
        for (int i = 0; i < 8; ++i) a8[i] = bf16b(af[i]);

        // issue t+1 loads BEFORE MFMA: latency hides under compute
        f32x4 sf0[3], sf1[3];
        if (t < 7) {
            const int koff = (t + 1) * 32 * HW_;
#pragma unroll
            for (int s = 0; s < 3; ++s) {
                f32x4 v0 = (f32x4){0.f, 0.f, 0.f, 0.f}, v1 = v0;
                if (gof0[s] != INT_MIN) {
                    v0 = *(const f32x4*)(in2n + gof0[s] + koff);
                    v1 = *(const f32x4*)(in2n + gof0[s] + koff + HW_);
                }
                sf0[s] = v0; sf1[s] = v1;
            }
#pragma unroll
            for (int i = 0; i < 8; ++i) af[i] = in1n[abase + koff + i * HW_];
        }

        // MFMA: wave wid, dy -> in2 LDS row r = wid+dy (rotated b128 reads)
#pragma unroll
        for (int dy = 0; dy < 9; ++dy) {
            int rj   = (wid + dy) * 4 + g;
            int base = rj * 128;
            int rot  = (rj & 7) << 2;
#pragma unroll
            for (int nt = 0; nt < 2; ++nt) {
                int dw = base + ((((nt * 16 + m) << 2) + rot) & 127);
                short8v b = *(const short8v*)&lds[dw * 2];
                acc[dy][nt] = MFMA32(a8, b, acc[dy][nt]);
            }
        }

        // pack t+1 (waits on its loads; barrier would wait anyway)
        if (t < 7) {
#pragma unroll
            for (int s = 0; s < 3; ++s)
#pragma unroll
                for (int d = 0; d < 4; ++d)
                    sp[s][d] = bf16pk(sf0[s][d], sf1[s][d]);
        }
        __syncthreads();
        __builtin_amdgcn_sched_barrier(0);
    }

    // ---- epilogue: one barrier pair; all 81 bands -> ldso -> coalesced stores ----
#pragma unroll
    for (int dy = 0; dy < 9; ++dy) {
#pragma unroll
        for (int nt = 0; nt < 2; ++nt) {
#pragma unroll
            for (int i = 0; i < 4; ++i) {
                int mm = 4 * g + i;              // D row = pixel w offset
                int dx = nt * 16 + m - mm;       // D col = mm + dx
                if (dx >= 0 && dx < 9)
                    ldso[(dy * 9 + dx) * 260 + wid * 16 + mm] = acc[dy][nt][i];
            }
        }
    }
    __syncthreads();
    __builtin_amdgcn_sched_barrier(0);
    const size_t outb = (size_t)n * 81 * HW_;
#pragma unroll
    for (int e = 0; e < 21; ++e) {
        int t2 = tid + e * 1024;
        if (t2 < 20736) {
            int dydx = t2 >> 8;                  // dy*9+dx
            int rem  = t2 & 255;                 // row*16 + w
            out[outb + (size_t)dydx * HW_ +
                (size_t)(h0 + (rem >> 4)) * W_ + (w0 + (rem & 15))] = ldso[dydx * 260 + rem];
        }
    }
}

extern "C" void kernel_launch(void* const* d_in, const int* in_sizes, int n_in,
                              void* d_out, int out_size, void* d_ws, size_t ws_size,
                              hipStream_t stream) {
    const float* in1 = (const float*)d_in[0];
    const float* in2 = (const float*)d_in[1];
    float* out = (float*)d_out;
    corr_kernel<<<dim3(512), dim3(1024), 0, stream>>>(in1, in2, out);
}

// Round 10
// 191.609 us; speedup vs baseline: 1.0848x; 1.0848x over previous
//
#include <hip/hip_runtime.h>
#include <limits.h>

typedef __attribute__((ext_vector_type(8))) short short8v;
typedef __attribute__((ext_vector_type(4))) float f32x4;

#define W_  128
#define HW_ 16384

#define MFMA32(a, b, c) __builtin_amdgcn_mfma_f32_16x16x32_bf16(a, b, c, 0, 0, 0)

__device__ __forceinline__ short bf16b(float f) {
    unsigned u = __float_as_uint(f);
    u += 0x7fffu + ((u >> 16) & 1u);   // RNE
    return (short)(u >> 16);
}
__device__ __forceinline__ unsigned bf16pk(float lo, float hi) {
    unsigned ul = __float_as_uint(lo);
    ul += 0x7fffu + ((ul >> 16) & 1u);
    unsigned uh = __float_as_uint(hi);
    uh += 0x7fffu + ((uh >> 16) & 1u);
    return (ul >> 16) | (uh & 0xffff0000u);
}

// 512 threads = 8 waves; tile 8h x 16w, all 81 displacements; 1 row/wave.
// acc[9][2] = 72 regs; amdgpu_waves_per_eu(4) caps unified regs at 128 ->
// 4 waves/SIMD. LDS 43KB -> 2 blocks/CU co-resident (independent barrier
// domains). Rounds 8/9 lesson: 1024-thread blocks intrinsically force the
// 128-reg cap while needing ~200 -> unavoidable acc spill (WRITE 100-200MB);
// 512-thread + small acc is the only geometry that can reach 4 waves/SIMD.
// Staging (validated r8/r9, absmax 0.5): 16 in2 rows x 32ch chunk, pair-packed
// bf16 dwords, per-(r,j) rotation ROT=((rj&7)<<2) mod 128 on write and read.
// Junk cols 24..31 never written; feed only never-stored acc elements.
// NOTE: all acc[][] indices compile-time constant (round-3 lesson: runtime
// index -> scratch demotion).
__global__ __launch_bounds__(512) __attribute__((amdgpu_waves_per_eu(4)))
void corr_kernel(const float* __restrict__ in1, const float* __restrict__ in2,
                 float* __restrict__ out)
{
    // stage view: 64 rj-rows x 128 dwords = 32KB; epilogue view: 81*132 floats
    // = 42768B aliased on top (used only after the loop's final barrier).
    __shared__ __attribute__((aligned(16))) unsigned char smem[43008];
    short*    lds  = (short*)smem;
    unsigned* ldsI = (unsigned*)smem;
    float*    ldso = (float*)smem;

    const int tid  = threadIdx.x;
    const int lane = tid & 63;
    const int wid  = tid >> 6;        // 0..7 = output row within tile
    const int m    = lane & 15;       // M row / N col in 16x16 tile
    const int g    = lane >> 4;       // k-octet 0..3

    // 1024 blocks: bijective XCD swizzle, image n = XCD; w-tiles fastest.
    int bid = blockIdx.x;
    int swz = (bid & 7) * 128 + (bid >> 3);
    int n   = swz >> 7;               // 0..7
    int h0  = ((swz >> 3) & 15) << 3; // 0,8,...,120
    int w0  = (swz & 7) << 4;         // 0,16,...,112

    const float* in1n = in1 + (size_t)n * (256 * HW_);
    const float* in2n = in2 + (size_t)n * (256 * HW_);

    // ---- staging geometry: pair-unit u = (r*16+kp)*6+q; 16*16*6 = 1536 = 3*512
    // (no activity predicate needed). Unit: row r(0..15), k-pair kp, cols 4q..4q+3.
    int gof0[3], wbas[3], wrot[3];
#pragma unroll
    for (int s = 0; s < 3; ++s) {
        int u    = tid + s * 512;
        int q    = u % 6;
        int rest = u / 6;             // 0..255
        int kp   = rest & 15;
        int r    = rest >> 4;         // 0..15
        int row  = h0 - 4 + r;
        int col0 = w0 - 4 + 4 * q;
        bool inb = ((unsigned)row < 128u) && ((unsigned)col0 < 125u);
        int  cc  = 8 * (kp >> 2) + 2 * (kp & 3);
        gof0[s]  = inb ? (cc * HW_ + row * W_ + col0) : INT_MIN;
        int rj   = r * 4 + (kp >> 2); // 0..63
        wbas[s]  = rj * 128;
        wrot[s]  = 16 * q + (kp & 3) + ((rj & 7) << 2);
    }
    const int abase = (8 * g) * HW_ + (h0 + wid) * W_ + (w0 + m);

    f32x4 acc[9][2];
#pragma unroll
    for (int d = 0; d < 9; ++d)
#pragma unroll
        for (int t = 0; t < 2; ++t)
            acc[d][t] = (f32x4){0.f, 0.f, 0.f, 0.f};

    // ---- prologue: load+pack chunk 0 (in2 -> sp, A -> a8n) ----
    unsigned sp[3][4];
    unsigned a8n[4];
    {
        f32x4 sf0[3], sf1[3];
        float af[8];
#pragma unroll
        for (int s = 0; s < 3; ++s) {
            f32x4 v0 = (f32x4){0.f, 0.f, 0.f, 0.f}, v1 = v0;
            if (gof0[s] != INT_MIN) {
                v0 = *(const f32x4*)(in2n + gof0[s]);
                v1 = *(const f32x4*)(in2n + gof0[s] + HW_);
            }
            sf0[s] = v0; sf1[s] = v1;
        }
#pragma unroll
        for (int i = 0; i < 8; ++i) af[i] = in1n[abase + i * HW_];
#pragma unroll
        for (int s = 0; s < 3; ++s)
#pragma unroll
            for (int d = 0; d < 4; ++d)
                sp[s][d] = bf16pk(sf0[s][d], sf1[s][d]);
#pragma unroll
        for (int d = 0; d < 4; ++d)
            a8n[d] = bf16pk(af[2 * d], af[2 * d + 1]);
    }

    // ---- main loop: 8 chunks of 32 channels; 2 barriers per chunk ----
#pragma unroll 1
    for (int t = 0; t < 8; ++t) {
        // stage chunk t (rotated pair-packed dword writes)
#pragma unroll
        for (int s = 0; s < 3; ++s)
#pragma unroll
            for (int d = 0; d < 4; ++d)
                ldsI[wbas[s] + ((wrot[s] + 4 * d) & 127)] = sp[s][d];
        __syncthreads();
        __builtin_amdgcn_sched_barrier(0);

        // A frag for chunk t (packed last iteration)
        short8v a8;
#pragma unroll
        for (int d = 0; d < 4; ++d) {
            a8[2 * d]     = (short)(a8n[d] & 0xffffu);
            a8[2 * d + 1] = (short)(a8n[d] >> 16);
        }

        // issue t+1 loads BEFORE MFMA (latency hides under compute)
        f32x4 sf0[3], sf1[3];
        float af[8];
        if (t < 7) {
            const int koff = (t + 1) * 32 * HW_;
#pragma unroll
            for (int s = 0; s < 3; ++s) {
                f32x4 v0 = (f32x4){0.f, 0.f, 0.f, 0.f}, v1 = v0;
                if (gof0[s] != INT_MIN) {
                    v0 = *(const f32x4*)(in2n + gof0[s] + koff);
                    v1 = *(const f32x4*)(in2n + gof0[s] + koff + HW_);
                }
                sf0[s] = v0; sf1[s] = v1;
            }
#pragma unroll
            for (int i = 0; i < 8; ++i) af[i] = in1n[abase + koff + i * HW_];
        }

        // MFMA: wave wid, dy -> in2 LDS row r = wid+dy (rotated b128 reads)
#pragma unroll
        for (int dy = 0; dy < 9; ++dy) {
            int rj   = (wid + dy) * 4 + g;
            int base = rj * 128;
            int rot  = (rj & 7) << 2;
#pragma unroll
            for (int nt = 0; nt < 2; ++nt) {
                int dw = base + ((((nt * 16 + m) << 2) + rot) & 127);
                short8v b = *(const short8v*)&lds[dw * 2];
                acc[dy][nt] = MFMA32(a8, b, acc[dy][nt]);
            }
        }

        // pack t+1 (waits on its loads; the barrier would wait anyway)
        if (t < 7) {
#pragma unroll
            for (int s = 0; s < 3; ++s)
#pragma unroll
                for (int d = 0; d < 4; ++d)
                    sp[s][d] = bf16pk(sf0[s][d], sf1[s][d]);
#pragma unroll
            for (int d = 0; d < 4; ++d)
                a8n[d] = bf16pk(af[2 * d], af[2 * d + 1]);
        }
        __syncthreads();
        __builtin_amdgcn_sched_barrier(0);
    }

    // ---- epilogue: one barrier pair; all 81 bands -> ldso -> coalesced stores ----
    // (loop's final barrier separates last MFMA reads from aliased ldso writes)
#pragma unroll
    for (int dy = 0; dy < 9; ++dy) {
#pragma unroll
        for (int nt = 0; nt < 2; ++nt) {
#pragma unroll
            for (int i = 0; i < 4; ++i) {
                int mm = 4 * g + i;              // D row = pixel w offset
                int dx = nt * 16 + m - mm;       // D col = mm + dx
                if (dx >= 0 && dx < 9)
                    ldso[(dy * 9 + dx) * 132 + wid * 16 + mm] = acc[dy][nt][i];
            }
        }
    }
    __syncthreads();
    __builtin_amdgcn_sched_barrier(0);
    const size_t outb = (size_t)n * 81 * HW_;
#pragma unroll
    for (int e = 0; e < 21; ++e) {
        int t2 = tid + e * 512;
        if (t2 < 10368) {
            int dydx = t2 >> 7;                  // dy*9+dx
            int rem  = t2 & 127;                 // row*16 + w
            out[outb + (size_t)dydx * HW_ +
                (size_t)(h0 + (rem >> 4)) * W_ + (w0 + (rem & 15))] = ldso[dydx * 132 + rem];
        }
    }
}

extern "C" void kernel_launch(void* const* d_in, const int* in_sizes, int n_in,
                              void* d_out, int out_size, void* d_ws, size_t ws_size,
                              hipStream_t stream) {
    const float* in1 = (const float*)d_in[0];
    const float* in2 = (const float*)d_in[1];
    float* out = (float*)d_out;
    corr_kernel<<<dim3(1024), dim3(512), 0, stream>>>(in1, in2, out);
}

// Round 11
// 109.575 us; speedup vs baseline: 1.8969x; 1.7487x over previous
//
#include <hip/hip_runtime.h>
#include <limits.h>

typedef __attribute__((ext_vector_type(8))) short short8v;
typedef __attribute__((ext_vector_type(4))) float f32x4;

#define W_  128
#define HW_ 16384

#define MFMA32(a, b, c) __builtin_amdgcn_mfma_f32_16x16x32_bf16(a, b, c, 0, 0, 0)

__device__ __forceinline__ unsigned bf16pk(float lo, float hi) {
    unsigned ul = __float_as_uint(lo);
    ul += 0x7fffu + ((ul >> 16) & 1u);
    unsigned uh = __float_as_uint(hi);
    uh += 0x7fffu + ((uh >> 16) & 1u);
    return (ul >> 16) | (uh & 0xffff0000u);
}

// 512 thr = 8 waves = 4 rows x 2 nt; tile 4h x 16w, all 81 disp; grid 2048.
// dx-band SPLIT across wave pairs: wave (row4, nt) owns one 16-col N-tile ->
// acc[9] = 36 regs. Live set ~115 fits the 128-reg unified cap of
// __launch_bounds__(512,4) -> 4 waves/SIMD, 2 blocks/CU, 2 barrier domains.
// Rounds 8-10 lesson: the cap is VGPR+AGPR UNIFIED; acc>AGPR-half spills.
// Staging (validated r8-r10, absmax 0.5): 12 in2 rows x 32ch chunk, pair-
// packed bf16 dwords, per-rj rotation ROT=((rj&7)<<2) mod 128 write & read.
// Ping-pong 2x24KB, ONE barrier per chunk (r4-validated ordering).
// Junk cols 24..31 never written; feed only never-stored acc elements.
// NOTE: all acc[] indices compile-time constant (round-3 lesson).
__global__ __launch_bounds__(512, 4)
void corr_kernel(const float* __restrict__ in1, const float* __restrict__ in2,
                 float* __restrict__ out)
{
    // 2 x 6144 dwords ping-pong (48KB); epilogue view 81*68 floats (22KB) alias.
    __shared__ __attribute__((aligned(16))) unsigned char smem[49152];
    short*    lds  = (short*)smem;
    unsigned* ldsI = (unsigned*)smem;
    float*    ldso = (float*)smem;

    const int tid  = threadIdx.x;
    const int lane = tid & 63;
    const int wid  = tid >> 6;        // 0..7
    const int row4 = wid >> 1;        // 0..3 = output row within tile
    const int nt   = wid & 1;         // N-tile half of the dx band
    const int m    = lane & 15;       // M row / N col in 16x16 tile
    const int g    = lane >> 4;       // k-octet 0..3

    // 2048 blocks: XCD = image; k = w-tile fastest, then h-tile (L2 halo reuse)
    int bid = blockIdx.x;
    int n   = bid & 7;
    int k   = bid >> 3;               // 0..255
    int h0  = (k >> 3) << 2;          // 0,4,...,124
    int w0  = (k & 7) << 4;           // 0,16,...,112

    const float* in1n = in1 + (size_t)n * (256 * HW_);
    const float* in2n = in2 + (size_t)n * (256 * HW_);

    // ---- staging geometry: pair-unit u = (r*16+kp)*6+q; 12*16*6 = 1152 units ----
    int gof0[3], wbas[3], wrot[3];
    bool act[3];
#pragma unroll
    for (int s = 0; s < 3; ++s) {
        int u    = tid + s * 512;
        act[s]   = (u < 1152);
        int q    = u % 6;
        int rest = u / 6;
        int kp   = rest & 15;
        int r    = rest >> 4;         // 0..11 (garbage for inactive lanes)
        int row  = h0 - 4 + r;
        int col0 = w0 - 4 + 4 * q;
        bool inb = act[s] && ((unsigned)row < 128u) && ((unsigned)col0 < 125u);
        int  cc  = 8 * (kp >> 2) + 2 * (kp & 3);
        gof0[s]  = inb ? (cc * HW_ + row * W_ + col0) : INT_MIN;
        int rj   = r * 4 + (kp >> 2); // 0..47
        wbas[s]  = rj * 128;
        wrot[s]  = 16 * q + (kp & 3) + ((rj & 7) << 2);
    }
    const int abase = (8 * g) * HW_ + (h0 + row4) * W_ + (w0 + m);

    f32x4 acc[9];
#pragma unroll
    for (int d = 0; d < 9; ++d) acc[d] = (f32x4){0.f, 0.f, 0.f, 0.f};

    // ---- prologue: load+pack chunk 0 ----
    unsigned sp[3][4];
    unsigned a8n[4];
    {
        f32x4 sf0[3], sf1[3];
        float af[8];
#pragma unroll
        for (int s = 0; s < 3; ++s) {
            f32x4 v0 = (f32x4){0.f, 0.f, 0.f, 0.f}, v1 = v0;
            if (gof0[s] != INT_MIN) {
                v0 = *(const f32x4*)(in2n + gof0[s]);
                v1 = *(const f32x4*)(in2n + gof0[s] + HW_);
            }
            sf0[s] = v0; sf1[s] = v1;
        }
#pragma unroll
        for (int i = 0; i < 8; ++i) af[i] = in1n[abase + i * HW_];
#pragma unroll
        for (int s = 0; s < 3; ++s)
#pragma unroll
            for (int d = 0; d < 4; ++d) sp[s][d] = bf16pk(sf0[s][d], sf1[s][d]);
#pragma unroll
        for (int d = 0; d < 4; ++d) a8n[d] = bf16pk(af[2 * d], af[2 * d + 1]);
    }

    // ---- main loop: 8 chunks of 32 channels; ONE barrier per chunk ----
#pragma unroll 1
    for (int t = 0; t < 8; ++t) {
        // write staged chunk t into buf (t&1)
        unsigned* wp = ldsI + (t & 1) * 6144;
#pragma unroll
        for (int s = 0; s < 3; ++s)
            if (act[s]) {
#pragma unroll
                for (int d = 0; d < 4; ++d)
                    wp[wbas[s] + ((wrot[s] + 4 * d) & 127)] = sp[s][d];
            }
        __syncthreads();
        __builtin_amdgcn_sched_barrier(0);

        // A frag for chunk t
        short8v a8;
#pragma unroll
        for (int d = 0; d < 4; ++d) {
            a8[2 * d]     = (short)(a8n[d] & 0xffffu);
            a8[2 * d + 1] = (short)(a8n[d] >> 16);
        }

        // issue t+1 loads BEFORE MFMA (latency hides under compute)
        f32x4 sf0[3], sf1[3];
        float af[8];
        if (t < 7) {
            const int koff = (t + 1) * 32 * HW_;
#pragma unroll
            for (int s = 0; s < 3; ++s) {
                f32x4 v0 = (f32x4){0.f, 0.f, 0.f, 0.f}, v1 = v0;
                if (gof0[s] != INT_MIN) {
                    v0 = *(const f32x4*)(in2n + gof0[s] + koff);
                    v1 = *(const f32x4*)(in2n + gof0[s] + koff + HW_);
                }
                sf0[s] = v0; sf1[s] = v1;
            }
#pragma unroll
            for (int i = 0; i < 8; ++i) af[i] = in1n[abase + koff + i * HW_];
        }

        // MFMA: 9 per chunk; B row rj = (row4+dy)*4+g, cols nt*16+m (rotated)
        const short* lb = lds + (t & 1) * 12288;
#pragma unroll
        for (int dy = 0; dy < 9; ++dy) {
            int rj = (row4 + dy) * 4 + g;
            int dw = rj * 128 + ((((nt * 16 + m) << 2) + ((rj & 7) << 2)) & 127);
            short8v b = *(const short8v*)&lb[dw * 2];
            acc[dy] = MFMA32(a8, b, acc[dy]);
        }

        // pack t+1 (vmcnt waits land here, after MFMA issue)
        if (t < 7) {
#pragma unroll
            for (int s = 0; s < 3; ++s)
#pragma unroll
                for (int d = 0; d < 4; ++d) sp[s][d] = bf16pk(sf0[s][d], sf1[s][d]);
#pragma unroll
            for (int d = 0; d < 4; ++d) a8n[d] = bf16pk(af[2 * d], af[2 * d + 1]);
        }
    }

    // ---- epilogue: bands -> ldso (stride 68, aliases buf0; safe: last chunk
    // read buf1 and t=7's barrier ordered all earlier buf0 reads) ----
#pragma unroll
    for (int dy = 0; dy < 9; ++dy) {
#pragma unroll
        for (int i = 0; i < 4; ++i) {
            int mm = 4 * g + i;                  // D row = pixel w offset
            int dx = nt * 16 + m - mm;           // D col = mm + dx
            if (dx >= 0 && dx < 9)
                ldso[(dy * 9 + dx) * 68 + row4 * 16 + mm] = acc[dy][i];
        }
    }
    __syncthreads();
    __builtin_amdgcn_sched_barrier(0);
    const size_t outb = (size_t)n * 81 * HW_;
#pragma unroll
    for (int e = 0; e < 11; ++e) {
        int t2 = tid + e * 512;
        if (t2 < 5184) {
            int dydx = t2 >> 6;                  // dy*9+dx
            int rem  = t2 & 63;                  // row*16 + w
            out[outb + (size_t)dydx * HW_ +
                (size_t)(h0 + (rem >> 4)) * W_ + (w0 + (rem & 15))] = ldso[dydx * 68 + rem];
        }
    }
}

extern "C" void kernel_launch(void* const* d_in, const int* in_sizes, int n_in,
                              void* d_out, int out_size, void* d_ws, size_t ws_size,
                              hipStream_t stream) {
    const float* in1 = (const float*)d_in[0];
    const float* in2 = (const float*)d_in[1];
    float* out = (float*)d_out;
    corr_kernel<<<dim3(2048), dim3(512), 0, stream>>>(in1, in2, out);
}